// Round 14
// baseline (153.017 us; speedup 1.0000x reference)
//
#include <hip/hip_runtime.h>
#include <hip/hip_bf16.h>
#include <math.h>

#define N_NODES 50000
#define N_EDGES 800000
#define E2 (N_EDGES + N_NODES)
#define D 128

#define NB_LN 12500
#define NB_W 128

#define BSHIFT 8
#define NBUCK 196  // ceil(50000 / 256)
#define SCHUNK 4096
#define NB_SC ((E2 + SCHUNK - 1) / SCHUNK)   // 208
#define NSLICE ((N_NODES + NB_SC - 1) / NB_SC)  // 241
#define NB_GEMM (((N_NODES + 127) / 128) * 2)   // 782

typedef short short8 __attribute__((ext_vector_type(8)));
typedef float f32x4 __attribute__((ext_vector_type(4)));
typedef _Float16 h16x2 __attribute__((ext_vector_type(2)));
typedef _Float16 h16x8 __attribute__((ext_vector_type(8)));

__device__ __forceinline__ float waveReduceSum(float v) {
#pragma unroll
  for (int off = 32; off >= 1; off >>= 1) v += __shfl_xor(v, off);
  return v;
}

// Fused: LayerNorm->ReLU->hb + hnorm | W transpose+cvt | bucket+node counts.
__global__ void __launch_bounds__(256) k_pre(
    const float* __restrict__ x, const float* __restrict__ gamma,
    const float* __restrict__ beta, const float* __restrict__ Wl,
    const float* __restrict__ Wr, const int* __restrict__ ei,
    __hip_bfloat16* __restrict__ hb, float* __restrict__ hnorm,
    __hip_bfloat16* __restrict__ Wt, int* __restrict__ bcnt,
    int* __restrict__ deg) {
  const int b = blockIdx.x;
  if (b < NB_LN) {
    int wid = threadIdx.x >> 6;
    int lane = threadIdx.x & 63;
    int i = b * 4 + wid;
    const float2 xv = *(const float2*)&x[(size_t)i * D + lane * 2];
    float s = waveReduceSum(xv.x + xv.y);
    float mean = s * (1.0f / D);
    float d0 = xv.x - mean, d1 = xv.y - mean;
    float vs = waveReduceSum(d0 * d0 + d1 * d1);
    float rstd = rsqrtf(vs * (1.0f / D) + 1e-5f);
    const float2 g = *(const float2*)&gamma[lane * 2];
    const float2 bb = *(const float2*)&beta[lane * 2];
    float h0 = fmaxf(d0 * rstd * g.x + bb.x, 0.0f);
    float h1 = fmaxf(d1 * rstd * g.y + bb.y, 0.0f);
    __hip_bfloat162 hv;
    hv.x = __float2bfloat16(h0);
    hv.y = __float2bfloat16(h1);
    *(__hip_bfloat162*)&hb[(size_t)i * D + lane * 2] = hv;
    float ns = waveReduceSum(h0 * h0 + h1 * h1);
    if (lane == 0) hnorm[i] = sqrtf(ns);
  } else if (b < NB_LN + NB_W) {
    int local = b - NB_LN;
    int n = local * 2 + (threadIdx.x >> 7);
    int k = threadIdx.x & 127;
    float v = (n < D) ? Wl[(size_t)k * D + n] : Wr[(size_t)k * D + (n - D)];
    Wt[n * D + k] = __float2bfloat16(v);
  } else {
    __shared__ int c[256];
    const int t = threadIdx.x;
    c[t] = 0;
    __syncthreads();
    const int s0 = (b - NB_LN - NB_W) * SCHUNK;
#pragma unroll
    for (int k = 0; k < 16; ++k) {
      int e = s0 + t + k * 256;
      if (e < E2) {
        int dst = (e < N_EDGES) ? ei[N_EDGES + e] : (e - N_EDGES);
        atomicAdd(&c[dst >> BSHIFT], 1);
        atomicAdd(&deg[dst], 1);
      }
    }
    __syncthreads();
    if (c[t]) atomicAdd(&bcnt[t], c[t]);
  }
}

// Scatter (src,dst) pairs into bucket-grouped array (two-phase, disjoint
// range reservation). Appended: sliced LDS-aggregated degree histogram.
__global__ void __launch_bounds__(256) k_bscatter(const int* __restrict__ ei,
                                                  const int* __restrict__ bcnt,
                                                  int* __restrict__ cnt0,
                                                  int2* __restrict__ bucketed,
                                                  const int* __restrict__ deg,
                                                  int* __restrict__ hist) {
  __shared__ int c[256], base[256], sd[256];
  __shared__ int hh[128];
  const int t = threadIdx.x;
  const int own = (t < NBUCK) ? bcnt[t] : 0;
  sd[t] = own;
  c[t] = 0;
  if (t < 128) hh[t] = 0;
  __syncthreads();
  for (int off = 1; off < 256; off <<= 1) {
    int u = 0;
    if (t >= off) u = sd[t - off];
    __syncthreads();
    if (t >= off) sd[t] += u;
    __syncthreads();
  }
  const int boffL = sd[t] - own;  // exclusive prefix
  const int s0 = blockIdx.x * SCHUNK;
#pragma unroll
  for (int k = 0; k < 16; ++k) {
    int e = s0 + t + k * 256;
    if (e < E2) {
      int dst = (e < N_EDGES) ? ei[N_EDGES + e] : (e - N_EDGES);
      atomicAdd(&c[dst >> BSHIFT], 1);
    }
  }
  __syncthreads();
  if (t < NBUCK) {
    base[t] = c[t] ? (boffL + atomicAdd(&cnt0[t], c[t])) : 0;
    c[t] = 0;
  }
  __syncthreads();
#pragma unroll
  for (int k = 0; k < 16; ++k) {
    int e = s0 + t + k * 256;
    if (e < E2) {
      int src, dst;
      if (e < N_EDGES) {
        src = ei[e];
        dst = ei[N_EDGES + e];
      } else {
        src = dst = e - N_EDGES;
      }
      int bk = dst >> BSHIFT;
      int pos = base[bk] + atomicAdd(&c[bk], 1);
      bucketed[pos] = make_int2(src, dst);
    }
  }
  // ---- degree histogram over this block's node slice ----
  const int n0 = blockIdx.x * NSLICE;
  const int n1 = min(n0 + NSLICE, N_NODES);
  for (int n = n0 + t; n < n1; n += 256) atomicAdd(&hh[min(deg[n], 127)], 1);
  __syncthreads();
  if (t < 128 && hh[t]) atomicAdd(&hist[t], hh[t]);
}

// Fused middle kernel: [0,NBUCK) CSR build (degrees from deg[]);
// [NBUCK,NBUCK+NB_GEMM) bf16 MFMA GEMM; [.., +NBUCK) degree-sort perm build.
__global__ void __launch_bounds__(256) k_mid(
    const int2* __restrict__ bucketed, const int* __restrict__ bcnt,
    const int* __restrict__ deg, const int* __restrict__ hist,
    int* __restrict__ cnt2, int* __restrict__ perm,
    int* __restrict__ rowptr, int* __restrict__ csr,
    const __hip_bfloat16* __restrict__ hb, const __hip_bfloat16* __restrict__ Wt,
    const float* __restrict__ bL, const float* __restrict__ bR,
    _Float16* __restrict__ xlh, _Float16* __restrict__ xrh) {
  __shared__ char smem[65536];
  const int t = threadIdx.x;
  if (blockIdx.x < NBUCK) {
    // ---- CSR build for bucket b (degrees known; single bucketed pass) ----
    int* tsum = (int*)smem;     // 256
    int* cursor = tsum + 256;   // 256
    int* red = cursor + 256;    // 256
    const int b = blockIdx.x;
    const int base = b << BSHIFT;
    const int nnode = min(256, N_NODES - base);
    red[t] = (t < b) ? bcnt[t] : 0;
    __syncthreads();
    for (int off = 128; off >= 1; off >>= 1) {
      if (t < off) red[t] += red[t + off];
      __syncthreads();
    }
    const int e0 = red[0], e1 = red[0] + bcnt[b];
    if (b == 0) {
      if (t == 0) rowptr[N_NODES] = E2;
      if (t < 64) csr[E2 + t] = 0;  // sentinel pad
    }
    const int own = (t < nnode) ? deg[base + t] : 0;
    tsum[t] = own;
    __syncthreads();
    for (int off = 1; off < 256; off <<= 1) {
      int u = 0;
      if (t >= off) u = tsum[t - off];
      __syncthreads();
      if (t >= off) tsum[t] += u;
      __syncthreads();
    }
    const int ebase = e0 + tsum[t] - own;  // exclusive prefix
    cursor[t] = ebase;
    if (t < nnode) rowptr[base + t] = ebase;
    __syncthreads();
    for (int e = e0 + t; e < e1; e += 256) {
      int2 pr = bucketed[e];
      int pos = atomicAdd(&cursor[pr.y - base], 1);
      csr[pos] = pr.x;
    }
  } else if (blockIdx.x < NBUCK + NB_GEMM) {
    // ---- GEMM tile ----
    unsigned short* As = (unsigned short*)smem;  // 128*128
    unsigned short* Bs = As + 128 * 128;
    const int bid = blockIdx.x - NBUCK;
    const int row0 = (bid >> 1) * 128;
    const int nhalf = bid & 1;
    const unsigned short* hu = (const unsigned short*)hb;
    const unsigned short* wu = (const unsigned short*)Wt;
#pragma unroll
    for (int it = 0; it < 8; ++it) {
      int idx = t + it * 256;
      int r = idx >> 4, g = idx & 15;
      int gs = g ^ (r & 15);
      short8 av = {};
      int grow = row0 + r;
      if (grow < N_NODES) av = *(const short8*)&hu[(size_t)grow * D + g * 8];
      *(short8*)&As[r * 128 + gs * 8] = av;
      short8 bv = *(const short8*)&wu[(size_t)(nhalf * 128 + r) * D + g * 8];
      *(short8*)&Bs[r * 128 + gs * 8] = bv;
    }
    __syncthreads();
    const int w = t >> 6, lane = t & 63;
    const int wm = (w >> 1) * 64, wn = (w & 1) * 64;
    const int lr = lane & 15, lq = lane >> 4;
    f32x4 acc[4][4] = {};
#pragma unroll
    for (int kb = 0; kb < 4; ++kb) {
      short8 af[4], bfr[4];
#pragma unroll
      for (int mi = 0; mi < 4; ++mi) {
        int r = wm + mi * 16 + lr;
        int g = (kb * 4 + lq) ^ (r & 15);
        af[mi] = *(const short8*)&As[r * 128 + g * 8];
      }
#pragma unroll
      for (int ni = 0; ni < 4; ++ni) {
        int r = wn + ni * 16 + lr;
        int g = (kb * 4 + lq) ^ (r & 15);
        bfr[ni] = *(const short8*)&Bs[r * 128 + g * 8];
      }
#pragma unroll
      for (int mi = 0; mi < 4; ++mi)
#pragma unroll
        for (int ni = 0; ni < 4; ++ni)
          acc[mi][ni] = __builtin_amdgcn_mfma_f32_16x16x32_bf16(af[mi], bfr[ni],
                                                                acc[mi][ni], 0, 0, 0);
    }
    const float* bb = (nhalf == 0) ? bL : bR;
    _Float16* dst = (nhalf == 0) ? xlh : xrh;
#pragma unroll
    for (int mi = 0; mi < 4; ++mi) {
#pragma unroll
      for (int ni = 0; ni < 4; ++ni) {
#pragma unroll
        for (int r = 0; r < 4; ++r) {
          int row = row0 + wm + mi * 16 + lq * 4 + r;
          int col = wn + ni * 16 + lr;
          if (row < N_NODES)
            dst[(size_t)row * D + col] = (_Float16)(acc[mi][ni][r] + bb[col]);
        }
      }
    }
  } else {
    // ---- degree-sort perm build (counting sort, two-phase reservation) ----
    int* bbase = (int*)smem;  // 128: exclusive bin base (global)
    int* horig = bbase + 128; // 128: original hist
    int* bc = horig + 128;    // 128: block bin count / local cursor
    int* brsv = bc + 128;     // 128: reserved global base per bin
    const int pb = blockIdx.x - NBUCK - NB_GEMM;
    const int n0 = pb << 8;
    const int nnode = min(256, N_NODES - n0);
    if (t < 128) {
      int hv = hist[t];
      horig[t] = hv;
      bbase[t] = hv;
      bc[t] = 0;
    }
    __syncthreads();
    for (int off = 1; off < 128; off <<= 1) {
      int u = 0;
      if (t >= off && t < 128) u = bbase[t - off];
      __syncthreads();
      if (t >= off && t < 128) bbase[t] += u;
      __syncthreads();
    }
    if (t < 128) bbase[t] -= horig[t];  // exclusive
    __syncthreads();
    int d = 0;
    if (t < nnode) {
      d = min(deg[n0 + t], 127);
      atomicAdd(&bc[d], 1);
    }
    __syncthreads();
    if (t < 128) {
      brsv[t] = bc[t] ? (bbase[t] + atomicAdd(&cnt2[t], bc[t])) : 0;
      bc[t] = 0;
    }
    __syncthreads();
    if (t < nnode) {
      int slot = brsv[d] + atomicAdd(&bc[d], 1);
      perm[slot] = n0 + t;
    }
  }
}

// Fused GATv2 edge phase. One wave = 4 nodes (degree-sorted via perm so the
// quad has ~equal degrees), 16 lanes per node, 3 gathers in flight.
// csr sentinel-padded (unclamped pipeline reads). att pre-scaled by log2(e)
// -> exp2f. Packed f16 score+aggregation; S in f32.
__global__ void __launch_bounds__(256) k_node(
    const float* __restrict__ x, const _Float16* __restrict__ xlh,
    const _Float16* __restrict__ xrh, const float* __restrict__ hnorm,
    const int* __restrict__ rowptr, const int* __restrict__ csr,
    const int* __restrict__ perm, const float* __restrict__ att,
    const float* __restrict__ bias, const float* __restrict__ scale,
    float* __restrict__ out) {
  const int wid = threadIdx.x >> 6;
  const int lane = threadIdx.x & 63;
  const int g = lane >> 4;  // node subgroup 0..3
  const int q = lane & 15;  // dim quad: dims q*8 .. q*8+7 ; head = q>>2
  const int i = perm[blockIdx.x * 16 + wid * 4 + g];

  const h16x8 xrv = *(const h16x8*)(xrh + (size_t)i * D + q * 8);
  h16x2 xr2[4], at2[4];
  {
    const float LOG2E = 1.44269504f;
    const float4 a0 = *(const float4*)&att[q * 8];
    const float4 a1 = *(const float4*)&att[q * 8 + 4];
    at2[0] = (h16x2){(_Float16)(a0.x * LOG2E), (_Float16)(a0.y * LOG2E)};
    at2[1] = (h16x2){(_Float16)(a0.z * LOG2E), (_Float16)(a0.w * LOG2E)};
    at2[2] = (h16x2){(_Float16)(a1.x * LOG2E), (_Float16)(a1.y * LOG2E)};
    at2[3] = (h16x2){(_Float16)(a1.z * LOG2E), (_Float16)(a1.w * LOG2E)};
#pragma unroll
    for (int z = 0; z < 4; ++z) xr2[z] = (h16x2){xrv[2 * z], xrv[2 * z + 1]};
  }
  const h16x2 c02 = {(_Float16)0.2f, (_Float16)0.2f};

  const int e0 = rowptr[i], e1 = rowptr[i + 1];
  const int deg_ = e1 - e0;
  int maxdeg = deg_;  // ~= deg_ after degree sort
  maxdeg = max(maxdeg, __shfl_xor(maxdeg, 16));
  maxdeg = max(maxdeg, __shfl_xor(maxdeg, 32));

  h16x2 A2[4] = {};
  float S = 0.f;

  // 3-deep software pipeline; unclamped csr reads (sentinel pad, masked).
  int ja = csr[e0];
  h16x8 r0 = *(const h16x8*)(xlh + (size_t)ja * D + q * 8);
  int jb = csr[e0 + 1];
  h16x8 r1 = *(const h16x8*)(xlh + (size_t)jb * D + q * 8);
  int jc = csr[e0 + 2];
  h16x8 r2 = *(const h16x8*)(xlh + (size_t)jc * D + q * 8);
  int jd = csr[e0 + 3];

  for (int it = 0; it < maxdeg; ++it) {
    const h16x8 cur = r0;
    r0 = r1;
    r1 = r2;
    r2 = *(const h16x8*)(xlh + (size_t)jd * D + q * 8);
    jd = csr[e0 + it + 4];
    const bool ok = it < deg_;

    h16x2 v2[4];
    v2[0] = (h16x2){cur[0], cur[1]};
    v2[1] = (h16x2){cur[2], cur[3]};
    v2[2] = (h16x2){cur[4], cur[5]};
    v2[3] = (h16x2){cur[6], cur[7]};
    float sc = 0.f;
#pragma unroll
    for (int z = 0; z < 4; ++z) {
      h16x2 f = v2[z] + xr2[z];
      h16x2 lf = __builtin_elementwise_max(f, f * c02);
      sc = __builtin_amdgcn_fdot2(lf, at2[z], sc, false);
    }
    sc += __shfl_xor(sc, 1);
    sc += __shfl_xor(sc, 2);
    const float p = ok ? __builtin_exp2f(sc) : 0.f;
    S += p;
    const _Float16 ph = (_Float16)p;
    const h16x2 p2 = {ph, ph};
#pragma unroll
    for (int z = 0; z < 4; ++z) A2[z] = v2[z] * p2 + A2[z];
  }

  const float si = 1.0f / S;  // S per (node, head): uniform across each quad
  float o[8];
  float b8[8];
  *(float4*)&b8[0] = *(const float4*)&bias[q * 8];
  *(float4*)&b8[4] = *(const float4*)&bias[q * 8 + 4];
  float dot = 0.f;
#pragma unroll
  for (int z = 0; z < 4; ++z) {
    o[2 * z] = fmaf((float)A2[z][0], si, b8[2 * z]);
    o[2 * z + 1] = fmaf((float)A2[z][1], si, b8[2 * z + 1]);
    dot = fmaf(o[2 * z], o[2 * z], dot);
    dot = fmaf(o[2 * z + 1], o[2 * z + 1], dot);
  }
  // norm over this node's 16 lanes (each dim once)
#pragma unroll
  for (int off = 8; off >= 1; off >>= 1) dot += __shfl_xor(dot, off, 16);
  const float nrm = sqrtf(dot);
  const float gg = hnorm[i] * scale[0] / fmaxf(nrm, 1e-12f);

  float x8[8];
  *(float4*)&x8[0] = *(const float4*)&x[(size_t)i * D + q * 8];
  *(float4*)&x8[4] = *(const float4*)&x[(size_t)i * D + q * 8 + 4];
  float r8[8];
#pragma unroll
  for (int z = 0; z < 8; ++z) r8[z] = fmaf(o[z], gg, x8[z]);
  *(float4*)&out[(size_t)i * D + q * 8] = *(float4*)&r8[0];
  *(float4*)&out[(size_t)i * D + q * 8 + 4] = *(float4*)&r8[4];
}

extern "C" void kernel_launch(void* const* d_in, const int* in_sizes, int n_in,
                              void* d_out, int out_size, void* d_ws, size_t ws_size,
                              hipStream_t stream) {
  const float* x = (const float*)d_in[0];
  const int* ei = (const int*)d_in[1];
  const float* gamma = (const float*)d_in[2];
  const float* beta = (const float*)d_in[3];
  const float* Wl = (const float*)d_in[4];
  const float* bL = (const float*)d_in[5];
  const float* Wr = (const float*)d_in[6];
  const float* bR = (const float*)d_in[7];
  const float* att = (const float*)d_in[8];
  const float* bias = (const float*)d_in[9];
  const float* scale = (const float*)d_in[10];
  float* out = (float*)d_out;

  // workspace layout (~49.5 MB, 16B-aligned segments)
  int2* bucketed = (int2*)d_ws;         // E2 pairs
  int* csr = (int*)(bucketed + E2);     // E2 + 64 (sentinel pad)
  int* rowptr = csr + E2 + 64;          // N+1 (padded to N+16)
  int* bcnt = rowptr + N_NODES + 16;    // 256   <- memset zero from here
  int* cnt0 = bcnt + 256;               // 256
  int* hist = cnt0 + 256;               // 128
  int* cnt2 = hist + 128;               // 128
  int* deg = cnt2 + 128;                // N      (memset covers through deg)
  int* perm = deg + N_NODES;            // N
  float* hnorm = (float*)(perm + N_NODES);  // N
  __hip_bfloat16* hb = (__hip_bfloat16*)(hnorm + N_NODES);
  __hip_bfloat16* Wt = hb + (size_t)N_NODES * D;  // 256*128
  _Float16* xlh = (_Float16*)(Wt + 256 * D);
  _Float16* xrh = xlh + (size_t)N_NODES * D;

  hipMemsetAsync(bcnt, 0, (size_t)(256 + 256 + 128 + 128 + N_NODES) * sizeof(int),
                 stream);
  k_pre<<<NB_LN + NB_W + NB_SC, 256, 0, stream>>>(x, gamma, beta, Wl, Wr, ei, hb,
                                                  hnorm, Wt, bcnt, deg);
  k_bscatter<<<NB_SC, 256, 0, stream>>>(ei, bcnt, cnt0, bucketed, deg, hist);
  k_mid<<<NBUCK + NB_GEMM + NBUCK, 256, 0, stream>>>(bucketed, bcnt, deg, hist, cnt2,
                                                     perm, rowptr, csr, hb, Wt, bL,
                                                     bR, xlh, xrh);
  k_node<<<N_NODES / 16, 256, 0, stream>>>(x, xlh, xrh, hnorm, rowptr, csr, perm,
                                           att, bias, scale, out);
}

// Round 15
// 134.687 us; speedup vs baseline: 1.1361x; 1.1361x over previous
//
#include <hip/hip_runtime.h>
#include <hip/hip_bf16.h>
#include <math.h>

#define N_NODES 50000
#define N_EDGES 800000
#define E2 (N_EDGES + N_NODES)
#define D 128

#define NB_LN 12500
#define NB_W 128

#define BSHIFT 8
#define NBUCK 196  // ceil(50000 / 256)
#define SCHUNK 4096
#define NB_SC ((E2 + SCHUNK - 1) / SCHUNK)
#define NB_GEMM (((N_NODES + 127) / 128) * 2)  // 782

typedef short short8 __attribute__((ext_vector_type(8)));
typedef float f32x4 __attribute__((ext_vector_type(4)));
typedef _Float16 h16x2 __attribute__((ext_vector_type(2)));
typedef _Float16 h16x8 __attribute__((ext_vector_type(8)));

__device__ __forceinline__ float waveReduceSum(float v) {
#pragma unroll
  for (int off = 32; off >= 1; off >>= 1) v += __shfl_xor(v, off);
  return v;
}

// Fused: LayerNorm->ReLU->hb + hnorm | W transpose+cvt | bucket count.
__global__ void __launch_bounds__(256) k_pre(
    const float* __restrict__ x, const float* __restrict__ gamma,
    const float* __restrict__ beta, const float* __restrict__ Wl,
    const float* __restrict__ Wr, const int* __restrict__ ei,
    __hip_bfloat16* __restrict__ hb, float* __restrict__ hnorm,
    __hip_bfloat16* __restrict__ Wt, int* __restrict__ bcnt) {
  const int b = blockIdx.x;
  if (b < NB_LN) {
    int wid = threadIdx.x >> 6;
    int lane = threadIdx.x & 63;
    int i = b * 4 + wid;
    const float2 xv = *(const float2*)&x[(size_t)i * D + lane * 2];
    float s = waveReduceSum(xv.x + xv.y);
    float mean = s * (1.0f / D);
    float d0 = xv.x - mean, d1 = xv.y - mean;
    float vs = waveReduceSum(d0 * d0 + d1 * d1);
    float rstd = rsqrtf(vs * (1.0f / D) + 1e-5f);
    const float2 g = *(const float2*)&gamma[lane * 2];
    const float2 bb = *(const float2*)&beta[lane * 2];
    float h0 = fmaxf(d0 * rstd * g.x + bb.x, 0.0f);
    float h1 = fmaxf(d1 * rstd * g.y + bb.y, 0.0f);
    __hip_bfloat162 hv;
    hv.x = __float2bfloat16(h0);
    hv.y = __float2bfloat16(h1);
    *(__hip_bfloat162*)&hb[(size_t)i * D + lane * 2] = hv;
    float ns = waveReduceSum(h0 * h0 + h1 * h1);
    if (lane == 0) hnorm[i] = sqrtf(ns);
  } else if (b < NB_LN + NB_W) {
    int local = b - NB_LN;
    int n = local * 2 + (threadIdx.x >> 7);
    int k = threadIdx.x & 127;
    float v = (n < D) ? Wl[(size_t)k * D + n] : Wr[(size_t)k * D + (n - D)];
    Wt[n * D + k] = __float2bfloat16(v);
  } else {
    __shared__ int c[256];
    const int t = threadIdx.x;
    c[t] = 0;
    __syncthreads();
    const int s0 = (b - NB_LN - NB_W) * SCHUNK;
#pragma unroll
    for (int k = 0; k < 16; ++k) {
      int e = s0 + t + k * 256;
      if (e < E2) {
        int dst = (e < N_EDGES) ? ei[N_EDGES + e] : (e - N_EDGES);
        atomicAdd(&c[dst >> BSHIFT], 1);
      }
    }
    __syncthreads();
    if (c[t]) atomicAdd(&bcnt[t], c[t]);
  }
}

// Scatter (src,dst) pairs into bucket-grouped array. Per-block two-phase;
// bucket base offsets computed in-block from bcnt (LDS exclusive scan),
// disjoint ranges reserved via zero-initialized global cursors cnt0.
__global__ void __launch_bounds__(256) k_bscatter(const int* __restrict__ ei,
                                                  const int* __restrict__ bcnt,
                                                  int* __restrict__ cnt0,
                                                  int2* __restrict__ bucketed) {
  __shared__ int c[256], base[256], sd[256];
  const int t = threadIdx.x;
  const int own = (t < NBUCK) ? bcnt[t] : 0;
  sd[t] = own;
  c[t] = 0;
  __syncthreads();
  for (int off = 1; off < 256; off <<= 1) {
    int u = 0;
    if (t >= off) u = sd[t - off];
    __syncthreads();
    if (t >= off) sd[t] += u;
    __syncthreads();
  }
  const int boffL = sd[t] - own;  // exclusive prefix
  const int s0 = blockIdx.x * SCHUNK;
#pragma unroll
  for (int k = 0; k < 16; ++k) {
    int e = s0 + t + k * 256;
    if (e < E2) {
      int dst = (e < N_EDGES) ? ei[N_EDGES + e] : (e - N_EDGES);
      atomicAdd(&c[dst >> BSHIFT], 1);
    }
  }
  __syncthreads();
  if (t < NBUCK) {
    base[t] = c[t] ? (boffL + atomicAdd(&cnt0[t], c[t])) : 0;
    c[t] = 0;
  }
  __syncthreads();
#pragma unroll
  for (int k = 0; k < 16; ++k) {
    int e = s0 + t + k * 256;
    if (e < E2) {
      int src, dst;
      if (e < N_EDGES) {
        src = ei[e];
        dst = ei[N_EDGES + e];
      } else {
        src = dst = e - N_EDGES;
      }
      int bk = dst >> BSHIFT;
      int pos = base[bk] + atomicAdd(&c[bk], 1);
      bucketed[pos] = make_int2(src, dst);
    }
  }
}

// Fused middle kernel: blocks [0,NBUCK) build CSR (one block per 256-node
// bucket) AND a within-bucket degree-sorted node permutation (free: degrees
// already in LDS); blocks [NBUCK, NBUCK+NB_GEMM) run the bf16 MFMA GEMM.
// One static 64KB LDS block, reinterpreted per role. Block 0 also writes the
// csr sentinel pad.
__global__ void __launch_bounds__(256) k_mid(
    const int2* __restrict__ bucketed, const int* __restrict__ bcnt,
    int* __restrict__ rowptr, int* __restrict__ csr, int* __restrict__ perm,
    const __hip_bfloat16* __restrict__ hb, const __hip_bfloat16* __restrict__ Wt,
    const float* __restrict__ bL, const float* __restrict__ bR,
    _Float16* __restrict__ xlh, _Float16* __restrict__ xrh) {
  __shared__ char smem[65536];
  const int t = threadIdx.x;
  if (blockIdx.x < NBUCK) {
    // ---- CSR build for bucket b ----
    int* cnt = (int*)smem;      // 256
    int* tsum = cnt + 256;      // 256
    int* cursor = tsum + 256;   // 256
    int* red = cursor + 256;    // 256
    int* dhist = red + 256;     // 128
    int* dscan = dhist + 128;   // 128
    int* dcur = dscan + 128;    // 128
    const int b = blockIdx.x;
    const int base = b << BSHIFT;
    const int nnode = min(256, N_NODES - base);
    red[t] = (t < b) ? bcnt[t] : 0;
    cnt[t] = 0;
    if (t < 128) dhist[t] = 0;
    __syncthreads();
    for (int off = 128; off >= 1; off >>= 1) {
      if (t < off) red[t] += red[t + off];
      __syncthreads();
    }
    const int e0 = red[0], e1 = red[0] + bcnt[b];
    if (b == 0) {
      if (t == 0) rowptr[N_NODES] = E2;
      if (t < 64) csr[E2 + t] = 0;  // sentinel pad
    }
    for (int e = e0 + t; e < e1; e += 256) {
      int2 pr = bucketed[e];
      atomicAdd(&cnt[pr.y - base], 1);
    }
    __syncthreads();
    const int own = cnt[t];
    const int dbin = min(own, 127);
    if (t < nnode) atomicAdd(&dhist[dbin], 1);
    tsum[t] = own;
    __syncthreads();
    for (int off = 1; off < 256; off <<= 1) {
      int u = 0;
      if (t >= off) u = tsum[t - off];
      __syncthreads();
      if (t >= off) tsum[t] += u;
      __syncthreads();
    }
    // degree-bin exclusive scan (128 wide)
    if (t < 128) dscan[t] = dhist[t];
    __syncthreads();
    for (int off = 1; off < 128; off <<= 1) {
      int u = 0;
      if (t >= off && t < 128) u = dscan[t - off];
      __syncthreads();
      if (t >= off && t < 128) dscan[t] += u;
      __syncthreads();
    }
    if (t < 128) {
      dscan[t] -= dhist[t];  // exclusive
      dcur[t] = 0;
    }
    const int ebase = e0 + tsum[t] - own;  // exclusive prefix
    cursor[t] = ebase;
    if (t < nnode) rowptr[base + t] = ebase;
    __syncthreads();
    // within-bucket degree-sorted permutation (counting sort)
    if (t < nnode) {
      int slot = dscan[dbin] + atomicAdd(&dcur[dbin], 1);
      perm[base + slot] = base + t;
    }
    for (int e = e0 + t; e < e1; e += 256) {
      int2 pr = bucketed[e];
      int pos = atomicAdd(&cursor[pr.y - base], 1);
      csr[pos] = pr.x;
    }
  } else {
    // ---- GEMM tile ----
    unsigned short* As = (unsigned short*)smem;  // 128*128
    unsigned short* Bs = As + 128 * 128;
    const int bid = blockIdx.x - NBUCK;
    const int row0 = (bid >> 1) * 128;
    const int nhalf = bid & 1;
    const unsigned short* hu = (const unsigned short*)hb;
    const unsigned short* wu = (const unsigned short*)Wt;
#pragma unroll
    for (int it = 0; it < 8; ++it) {
      int idx = t + it * 256;
      int r = idx >> 4, g = idx & 15;
      int gs = g ^ (r & 15);
      short8 av = {};
      int grow = row0 + r;
      if (grow < N_NODES) av = *(const short8*)&hu[(size_t)grow * D + g * 8];
      *(short8*)&As[r * 128 + gs * 8] = av;
      short8 bv = *(const short8*)&wu[(size_t)(nhalf * 128 + r) * D + g * 8];
      *(short8*)&Bs[r * 128 + gs * 8] = bv;
    }
    __syncthreads();
    const int w = t >> 6, lane = t & 63;
    const int wm = (w >> 1) * 64, wn = (w & 1) * 64;
    const int lr = lane & 15, lq = lane >> 4;
    f32x4 acc[4][4] = {};
#pragma unroll
    for (int kb = 0; kb < 4; ++kb) {
      short8 af[4], bfr[4];
#pragma unroll
      for (int mi = 0; mi < 4; ++mi) {
        int r = wm + mi * 16 + lr;
        int g = (kb * 4 + lq) ^ (r & 15);
        af[mi] = *(const short8*)&As[r * 128 + g * 8];
      }
#pragma unroll
      for (int ni = 0; ni < 4; ++ni) {
        int r = wn + ni * 16 + lr;
        int g = (kb * 4 + lq) ^ (r & 15);
        bfr[ni] = *(const short8*)&Bs[r * 128 + g * 8];
      }
#pragma unroll
      for (int mi = 0; mi < 4; ++mi)
#pragma unroll
        for (int ni = 0; ni < 4; ++ni)
          acc[mi][ni] = __builtin_amdgcn_mfma_f32_16x16x32_bf16(af[mi], bfr[ni],
                                                                acc[mi][ni], 0, 0, 0);
    }
    const float* bb = (nhalf == 0) ? bL : bR;
    _Float16* dst = (nhalf == 0) ? xlh : xrh;
#pragma unroll
    for (int mi = 0; mi < 4; ++mi) {
#pragma unroll
      for (int ni = 0; ni < 4; ++ni) {
#pragma unroll
        for (int r = 0; r < 4; ++r) {
          int row = row0 + wm + mi * 16 + lq * 4 + r;
          int col = wn + ni * 16 + lr;
          if (row < N_NODES)
            dst[(size_t)row * D + col] = (_Float16)(acc[mi][ni][r] + bb[col]);
        }
      }
    }
  }
}

// Fused GATv2 edge phase. One wave = 4 nodes (within-bucket degree-sorted
// perm -> quads have near-equal degrees), 16 lanes per node, 3 gathers in
// flight. csr sentinel-padded (unclamped pipeline reads). att pre-scaled by
// log2(e) -> exp2f. Packed f16 score+aggregation; S in f32.
__global__ void __launch_bounds__(256) k_node(
    const float* __restrict__ x, const _Float16* __restrict__ xlh,
    const _Float16* __restrict__ xrh, const float* __restrict__ hnorm,
    const int* __restrict__ rowptr, const int* __restrict__ csr,
    const int* __restrict__ perm, const float* __restrict__ att,
    const float* __restrict__ bias, const float* __restrict__ scale,
    float* __restrict__ out) {
  const int wid = threadIdx.x >> 6;
  const int lane = threadIdx.x & 63;
  const int g = lane >> 4;  // node subgroup 0..3
  const int q = lane & 15;  // dim quad: dims q*8 .. q*8+7 ; head = q>>2
  const int i = perm[blockIdx.x * 16 + wid * 4 + g];  // N = 3125*16 exactly

  const h16x8 xrv = *(const h16x8*)(xrh + (size_t)i * D + q * 8);
  h16x2 xr2[4], at2[4];
  {
    const float LOG2E = 1.44269504f;
    const float4 a0 = *(const float4*)&att[q * 8];
    const float4 a1 = *(const float4*)&att[q * 8 + 4];
    at2[0] = (h16x2){(_Float16)(a0.x * LOG2E), (_Float16)(a0.y * LOG2E)};
    at2[1] = (h16x2){(_Float16)(a0.z * LOG2E), (_Float16)(a0.w * LOG2E)};
    at2[2] = (h16x2){(_Float16)(a1.x * LOG2E), (_Float16)(a1.y * LOG2E)};
    at2[3] = (h16x2){(_Float16)(a1.z * LOG2E), (_Float16)(a1.w * LOG2E)};
#pragma unroll
    for (int z = 0; z < 4; ++z) xr2[z] = (h16x2){xrv[2 * z], xrv[2 * z + 1]};
  }
  const h16x2 c02 = {(_Float16)0.2f, (_Float16)0.2f};

  const int e0 = rowptr[i], e1 = rowptr[i + 1];
  const int deg = e1 - e0;
  int maxdeg = deg;  // quads are degree-sorted: spread ~0-1
  maxdeg = max(maxdeg, __shfl_xor(maxdeg, 16));
  maxdeg = max(maxdeg, __shfl_xor(maxdeg, 32));

  h16x2 A2[4] = {};
  float S = 0.f;

  // 3-deep software pipeline; unclamped csr reads (sentinel pad, masked).
  int ja = csr[e0];
  h16x8 r0 = *(const h16x8*)(xlh + (size_t)ja * D + q * 8);
  int jb = csr[e0 + 1];
  h16x8 r1 = *(const h16x8*)(xlh + (size_t)jb * D + q * 8);
  int jc = csr[e0 + 2];
  h16x8 r2 = *(const h16x8*)(xlh + (size_t)jc * D + q * 8);
  int jd = csr[e0 + 3];

  for (int it = 0; it < maxdeg; ++it) {
    const h16x8 cur = r0;
    r0 = r1;
    r1 = r2;
    r2 = *(const h16x8*)(xlh + (size_t)jd * D + q * 8);
    jd = csr[e0 + it + 4];
    const bool ok = it < deg;

    h16x2 v2[4];
    v2[0] = (h16x2){cur[0], cur[1]};
    v2[1] = (h16x2){cur[2], cur[3]};
    v2[2] = (h16x2){cur[4], cur[5]};
    v2[3] = (h16x2){cur[6], cur[7]};
    float sc = 0.f;
#pragma unroll
    for (int z = 0; z < 4; ++z) {
      h16x2 f = v2[z] + xr2[z];
      h16x2 lf = __builtin_elementwise_max(f, f * c02);
      sc = __builtin_amdgcn_fdot2(lf, at2[z], sc, false);
    }
    sc += __shfl_xor(sc, 1);
    sc += __shfl_xor(sc, 2);
    const float p = ok ? __builtin_exp2f(sc) : 0.f;
    S += p;
    const _Float16 ph = (_Float16)p;
    const h16x2 p2 = {ph, ph};
#pragma unroll
    for (int z = 0; z < 4; ++z) A2[z] = v2[z] * p2 + A2[z];
  }

  const float si = 1.0f / S;  // S per (node, head): uniform across each quad
  float o[8];
  float b8[8];
  *(float4*)&b8[0] = *(const float4*)&bias[q * 8];
  *(float4*)&b8[4] = *(const float4*)&bias[q * 8 + 4];
  float dot = 0.f;
#pragma unroll
  for (int z = 0; z < 4; ++z) {
    o[2 * z] = fmaf((float)A2[z][0], si, b8[2 * z]);
    o[2 * z + 1] = fmaf((float)A2[z][1], si, b8[2 * z + 1]);
    dot = fmaf(o[2 * z], o[2 * z], dot);
    dot = fmaf(o[2 * z + 1], o[2 * z + 1], dot);
  }
  // norm over this node's 16 lanes (each dim once)
#pragma unroll
  for (int off = 8; off >= 1; off >>= 1) dot += __shfl_xor(dot, off, 16);
  const float nrm = sqrtf(dot);
  const float gg = hnorm[i] * scale[0] / fmaxf(nrm, 1e-12f);

  float x8[8];
  *(float4*)&x8[0] = *(const float4*)&x[(size_t)i * D + q * 8];
  *(float4*)&x8[4] = *(const float4*)&x[(size_t)i * D + q * 8 + 4];
  float r8[8];
#pragma unroll
  for (int z = 0; z < 8; ++z) r8[z] = fmaf(o[z], gg, x8[z]);
  *(float4*)&out[(size_t)i * D + q * 8] = *(float4*)&r8[0];
  *(float4*)&out[(size_t)i * D + q * 8 + 4] = *(float4*)&r8[4];
}

extern "C" void kernel_launch(void* const* d_in, const int* in_sizes, int n_in,
                              void* d_out, int out_size, void* d_ws, size_t ws_size,
                              hipStream_t stream) {
  const float* x = (const float*)d_in[0];
  const int* ei = (const int*)d_in[1];
  const float* gamma = (const float*)d_in[2];
  const float* beta = (const float*)d_in[3];
  const float* Wl = (const float*)d_in[4];
  const float* bL = (const float*)d_in[5];
  const float* Wr = (const float*)d_in[6];
  const float* bR = (const float*)d_in[7];
  const float* att = (const float*)d_in[8];
  const float* bias = (const float*)d_in[9];
  const float* scale = (const float*)d_in[10];
  float* out = (float*)d_out;

  // workspace layout (~49.2 MB, 16B-aligned segments)
  int2* bucketed = (int2*)d_ws;         // E2 pairs
  int* csr = (int*)(bucketed + E2);     // E2 + 64 (sentinel pad)
  int* rowptr = csr + E2 + 64;          // N+1 (padded to N+16)
  int* bcnt = rowptr + N_NODES + 16;    // 256   <- memset zero from here
  int* cnt0 = bcnt + 256;               // 256
  int* perm = cnt0 + 256;               // N
  float* hnorm = (float*)(perm + N_NODES);  // N
  __hip_bfloat16* hb = (__hip_bfloat16*)(hnorm + N_NODES);
  __hip_bfloat16* Wt = hb + (size_t)N_NODES * D;  // 256*128
  _Float16* xlh = (_Float16*)(Wt + 256 * D);
  _Float16* xrh = xlh + (size_t)N_NODES * D;

  hipMemsetAsync(bcnt, 0, 512 * sizeof(int), stream);
  k_pre<<<NB_LN + NB_W + NB_SC, 256, 0, stream>>>(x, gamma, beta, Wl, Wr, ei, hb,
                                                  hnorm, Wt, bcnt);
  k_bscatter<<<NB_SC, 256, 0, stream>>>(ei, bcnt, cnt0, bucketed);
  k_mid<<<NBUCK + NB_GEMM, 256, 0, stream>>>(bucketed, bcnt, rowptr, csr, perm, hb,
                                             Wt, bL, bR, xlh, xrh);
  k_node<<<N_NODES / 16, 256, 0, stream>>>(x, xlh, xrh, hnorm, rowptr, csr, perm,
                                           att, bias, scale, out);
}

// Round 16
// 109.919 us; speedup vs baseline: 1.3921x; 1.2253x over previous
//
#include <hip/hip_runtime.h>
#include <hip/hip_bf16.h>
#include <math.h>

#define N_NODES 50000
#define N_EDGES 800000
#define E2 (N_EDGES + N_NODES)
#define D 128

#define NB_LN 12500
#define NB_W 128

#define BSHIFT 8
#define NBUCK 196  // ceil(50000 / 256)
#define SCHUNK 4096
#define NB_SC ((E2 + SCHUNK - 1) / SCHUNK)
#define NB_GEMM (((N_NODES + 127) / 128) * 2)  // 782

typedef short short8 __attribute__((ext_vector_type(8)));
typedef float f32x4 __attribute__((ext_vector_type(4)));
typedef _Float16 h16x2 __attribute__((ext_vector_type(2)));
typedef _Float16 h16x8 __attribute__((ext_vector_type(8)));

__device__ __forceinline__ float waveReduceSum(float v) {
#pragma unroll
  for (int off = 32; off >= 1; off >>= 1) v += __shfl_xor(v, off);
  return v;
}

__device__ __forceinline__ h16x2 shfl_xor_h2(h16x2 v, int off) {
  int r = __shfl_xor(__builtin_bit_cast(int, v), off);
  return __builtin_bit_cast(h16x2, r);
}

// Bucket count only (fast; unblocks the CSR chain without waiting on LN).
__global__ void __launch_bounds__(256) k_count(const int* __restrict__ ei,
                                               int* __restrict__ bcnt) {
  __shared__ int c[256];
  const int t = threadIdx.x;
  c[t] = 0;
  __syncthreads();
  const int s0 = blockIdx.x * SCHUNK;
#pragma unroll
  for (int k = 0; k < 16; ++k) {
    int e = s0 + t + k * 256;
    if (e < E2) {
      int dst = (e < N_EDGES) ? ei[N_EDGES + e] : (e - N_EDGES);
      atomicAdd(&c[dst >> BSHIFT], 1);
    }
  }
  __syncthreads();
  if (c[t]) atomicAdd(&bcnt[t], c[t]);
}

// Fused: blocks [0,NB_SC) bucket-scatter (needs only bcnt);
// [NB_SC,+NB_LN) LayerNorm->ReLU->hb + hnorm; [..,+NB_W) W transpose+cvt.
__global__ void __launch_bounds__(256) k_pre2(
    const float* __restrict__ x, const float* __restrict__ gamma,
    const float* __restrict__ beta, const float* __restrict__ Wl,
    const float* __restrict__ Wr, const int* __restrict__ ei,
    const int* __restrict__ bcnt, int* __restrict__ cnt0,
    int2* __restrict__ bucketed, __hip_bfloat16* __restrict__ hb,
    float* __restrict__ hnorm, __hip_bfloat16* __restrict__ Wt) {
  const int b = blockIdx.x;
  if (b < NB_SC) {
    // ---- bucket scatter (two-phase, disjoint range reservation) ----
    __shared__ int c[256], base[256], sd[256];
    const int t = threadIdx.x;
    const int own = (t < NBUCK) ? bcnt[t] : 0;
    sd[t] = own;
    c[t] = 0;
    __syncthreads();
    for (int off = 1; off < 256; off <<= 1) {
      int u = 0;
      if (t >= off) u = sd[t - off];
      __syncthreads();
      if (t >= off) sd[t] += u;
      __syncthreads();
    }
    const int boffL = sd[t] - own;  // exclusive prefix
    const int s0 = b * SCHUNK;
#pragma unroll
    for (int k = 0; k < 16; ++k) {
      int e = s0 + t + k * 256;
      if (e < E2) {
        int dst = (e < N_EDGES) ? ei[N_EDGES + e] : (e - N_EDGES);
        atomicAdd(&c[dst >> BSHIFT], 1);
      }
    }
    __syncthreads();
    if (t < NBUCK) {
      base[t] = c[t] ? (boffL + atomicAdd(&cnt0[t], c[t])) : 0;
      c[t] = 0;
    }
    __syncthreads();
#pragma unroll
    for (int k = 0; k < 16; ++k) {
      int e = s0 + t + k * 256;
      if (e < E2) {
        int src, dst;
        if (e < N_EDGES) {
          src = ei[e];
          dst = ei[N_EDGES + e];
        } else {
          src = dst = e - N_EDGES;
        }
        int bk = dst >> BSHIFT;
        int pos = base[bk] + atomicAdd(&c[bk], 1);
        bucketed[pos] = make_int2(src, dst);
      }
    }
  } else if (b < NB_SC + NB_LN) {
    int wid = threadIdx.x >> 6;
    int lane = threadIdx.x & 63;
    int i = (b - NB_SC) * 4 + wid;
    const float2 xv = *(const float2*)&x[(size_t)i * D + lane * 2];
    float s = waveReduceSum(xv.x + xv.y);
    float mean = s * (1.0f / D);
    float d0 = xv.x - mean, d1 = xv.y - mean;
    float vs = waveReduceSum(d0 * d0 + d1 * d1);
    float rstd = rsqrtf(vs * (1.0f / D) + 1e-5f);
    const float2 g = *(const float2*)&gamma[lane * 2];
    const float2 bb = *(const float2*)&beta[lane * 2];
    float h0 = fmaxf(d0 * rstd * g.x + bb.x, 0.0f);
    float h1 = fmaxf(d1 * rstd * g.y + bb.y, 0.0f);
    __hip_bfloat162 hv;
    hv.x = __float2bfloat16(h0);
    hv.y = __float2bfloat16(h1);
    *(__hip_bfloat162*)&hb[(size_t)i * D + lane * 2] = hv;
    float ns = waveReduceSum(h0 * h0 + h1 * h1);
    if (lane == 0) hnorm[i] = sqrtf(ns);
  } else {
    int local = b - NB_SC - NB_LN;
    int n = local * 2 + (threadIdx.x >> 7);
    int k = threadIdx.x & 127;
    float v = (n < D) ? Wl[(size_t)k * D + n] : Wr[(size_t)k * D + (n - D)];
    Wt[n * D + k] = __float2bfloat16(v);
  }
}

// Fused middle kernel: blocks [0,NBUCK) build CSR (one block per 256-node
// bucket); blocks [NBUCK, NBUCK+NB_GEMM) run the bf16 MFMA GEMM.
// One static 64KB LDS block, reinterpreted per role. Block 0 also writes the
// csr sentinel pad (k_node reads up to ~csr[E2+19] unclamped).
__global__ void __launch_bounds__(256) k_mid(
    const int2* __restrict__ bucketed, const int* __restrict__ bcnt,
    int* __restrict__ rowptr, int* __restrict__ csr,
    const __hip_bfloat16* __restrict__ hb, const __hip_bfloat16* __restrict__ Wt,
    const float* __restrict__ bL, const float* __restrict__ bR,
    _Float16* __restrict__ xlh, _Float16* __restrict__ xrh) {
  __shared__ char smem[65536];
  const int t = threadIdx.x;
  if (blockIdx.x < NBUCK) {
    // ---- CSR build for bucket b ----
    int* cnt = (int*)smem;     // 256
    int* tsum = cnt + 256;     // 256
    int* cursor = tsum + 256;  // 256
    int* red = cursor + 256;   // 256
    const int b = blockIdx.x;
    const int base = b << BSHIFT;
    const int nnode = min(256, N_NODES - base);
    red[t] = (t < b) ? bcnt[t] : 0;
    cnt[t] = 0;
    __syncthreads();
    for (int off = 128; off >= 1; off >>= 1) {
      if (t < off) red[t] += red[t + off];
      __syncthreads();
    }
    const int e0 = red[0], e1 = red[0] + bcnt[b];
    if (b == 0) {
      if (t == 0) rowptr[N_NODES] = E2;
      if (t < 32) csr[E2 + t] = 0;  // sentinel pad
    }
    for (int e = e0 + t; e < e1; e += 256) {
      int2 pr = bucketed[e];
      atomicAdd(&cnt[pr.y - base], 1);
    }
    __syncthreads();
    const int own = cnt[t];
    tsum[t] = own;
    __syncthreads();
    for (int off = 1; off < 256; off <<= 1) {
      int u = 0;
      if (t >= off) u = tsum[t - off];
      __syncthreads();
      if (t >= off) tsum[t] += u;
      __syncthreads();
    }
    const int ebase = e0 + tsum[t] - own;  // exclusive prefix
    cursor[t] = ebase;
    if (t < nnode) rowptr[base + t] = ebase;
    __syncthreads();
    for (int e = e0 + t; e < e1; e += 256) {
      int2 pr = bucketed[e];
      int pos = atomicAdd(&cursor[pr.y - base], 1);
      csr[pos] = pr.x;
    }
  } else {
    // ---- GEMM tile ----
    unsigned short* As = (unsigned short*)smem;  // 128*128
    unsigned short* Bs = As + 128 * 128;
    const int bid = blockIdx.x - NBUCK;
    const int row0 = (bid >> 1) * 128;
    const int nhalf = bid & 1;
    const unsigned short* hu = (const unsigned short*)hb;
    const unsigned short* wu = (const unsigned short*)Wt;
#pragma unroll
    for (int it = 0; it < 8; ++it) {
      int idx = t + it * 256;
      int r = idx >> 4, g = idx & 15;
      int gs = g ^ (r & 15);
      short8 av = {};
      int grow = row0 + r;
      if (grow < N_NODES) av = *(const short8*)&hu[(size_t)grow * D + g * 8];
      *(short8*)&As[r * 128 + gs * 8] = av;
      short8 bv = *(const short8*)&wu[(size_t)(nhalf * 128 + r) * D + g * 8];
      *(short8*)&Bs[r * 128 + gs * 8] = bv;
    }
    __syncthreads();
    const int w = t >> 6, lane = t & 63;
    const int wm = (w >> 1) * 64, wn = (w & 1) * 64;
    const int lr = lane & 15, lq = lane >> 4;
    f32x4 acc[4][4] = {};
#pragma unroll
    for (int kb = 0; kb < 4; ++kb) {
      short8 af[4], bfr[4];
#pragma unroll
      for (int mi = 0; mi < 4; ++mi) {
        int r = wm + mi * 16 + lr;
        int g = (kb * 4 + lq) ^ (r & 15);
        af[mi] = *(const short8*)&As[r * 128 + g * 8];
      }
#pragma unroll
      for (int ni = 0; ni < 4; ++ni) {
        int r = wn + ni * 16 + lr;
        int g = (kb * 4 + lq) ^ (r & 15);
        bfr[ni] = *(const short8*)&Bs[r * 128 + g * 8];
      }
#pragma unroll
      for (int mi = 0; mi < 4; ++mi)
#pragma unroll
        for (int ni = 0; ni < 4; ++ni)
          acc[mi][ni] = __builtin_amdgcn_mfma_f32_16x16x32_bf16(af[mi], bfr[ni],
                                                                acc[mi][ni], 0, 0, 0);
    }
    const float* bb = (nhalf == 0) ? bL : bR;
    _Float16* dst = (nhalf == 0) ? xlh : xrh;
#pragma unroll
    for (int mi = 0; mi < 4; ++mi) {
#pragma unroll
      for (int ni = 0; ni < 4; ++ni) {
#pragma unroll
        for (int r = 0; r < 4; ++r) {
          int row = row0 + wm + mi * 16 + lq * 4 + r;
          int col = wn + ni * 16 + lr;
          if (row < N_NODES)
            dst[(size_t)row * D + col] = (_Float16)(acc[mi][ni][r] + bb[col]);
        }
      }
    }
  }
}

// Fused GATv2 edge phase. One wave per node; 4 edges per iteration
// (16 lanes/edge, 8 dims/lane), gathers prefetched 3 iterations deep.
// csr is sentinel-padded so the pipeline reads unclamped (masked via ok).
// att pre-scaled by log2(e) -> exp2f (v_exp_f32 directly). Packed f16
// score+aggregation math; S in f32. Direct exp is fp32-safe (scores O(+-3),
// softmax shift-invariant).
__global__ void __launch_bounds__(256) k_node(
    const float* __restrict__ x, const _Float16* __restrict__ xlh,
    const _Float16* __restrict__ xrh, const float* __restrict__ hnorm,
    const int* __restrict__ rowptr, const int* __restrict__ csr,
    const float* __restrict__ att, const float* __restrict__ bias,
    const float* __restrict__ scale, float* __restrict__ out) {
  const int wid = threadIdx.x >> 6;
  const int lane = threadIdx.x & 63;
  const int i = blockIdx.x * 4 + wid;
  if (i >= N_NODES) return;
  const int g = lane >> 4;  // edge subgroup 0..3
  const int q = lane & 15;  // dim quad: dims q*8 .. q*8+7 ; head = q>>2

  const h16x8 xrv = *(const h16x8*)(xrh + (size_t)i * D + q * 8);
  h16x2 xr2[4], at2[4];
  {
    const float LOG2E = 1.44269504f;
    const float4 a0 = *(const float4*)&att[q * 8];
    const float4 a1 = *(const float4*)&att[q * 8 + 4];
    at2[0] = (h16x2){(_Float16)(a0.x * LOG2E), (_Float16)(a0.y * LOG2E)};
    at2[1] = (h16x2){(_Float16)(a0.z * LOG2E), (_Float16)(a0.w * LOG2E)};
    at2[2] = (h16x2){(_Float16)(a1.x * LOG2E), (_Float16)(a1.y * LOG2E)};
    at2[3] = (h16x2){(_Float16)(a1.z * LOG2E), (_Float16)(a1.w * LOG2E)};
#pragma unroll
    for (int z = 0; z < 4; ++z) xr2[z] = (h16x2){xrv[2 * z], xrv[2 * z + 1]};
  }
  const h16x2 c02 = {(_Float16)0.2f, (_Float16)0.2f};

  const int e0 = rowptr[i], e1 = rowptr[i + 1];
  h16x2 A2[4] = {};
  float S = 0.f;

  // 3-deep software pipeline: three row-gathers in flight per lane.
  // Unclamped csr reads run into the next segment / sentinel pad (valid
  // memory, row indices always in [0,N)); contributions masked via ok.
  int ja = csr[e0 + g];
  h16x8 r0 = *(const h16x8*)(xlh + (size_t)ja * D + q * 8);
  int jb = csr[e0 + 4 + g];
  h16x8 r1 = *(const h16x8*)(xlh + (size_t)jb * D + q * 8);
  int jc = csr[e0 + 8 + g];
  h16x8 r2 = *(const h16x8*)(xlh + (size_t)jc * D + q * 8);
  int jd = csr[e0 + 12 + g];

  for (int e = e0; e < e1; e += 4) {
    const h16x8 cur = r0;
    r0 = r1;
    r1 = r2;
    r2 = *(const h16x8*)(xlh + (size_t)jd * D + q * 8);
    jd = csr[e + 16 + g];
    const bool ok = (e + g) < e1;

    h16x2 v2[4];
    v2[0] = (h16x2){cur[0], cur[1]};
    v2[1] = (h16x2){cur[2], cur[3]};
    v2[2] = (h16x2){cur[4], cur[5]};
    v2[3] = (h16x2){cur[6], cur[7]};
    float sc = 0.f;
#pragma unroll
    for (int z = 0; z < 4; ++z) {
      h16x2 f = v2[z] + xr2[z];
      h16x2 lf = __builtin_elementwise_max(f, f * c02);
      sc = __builtin_amdgcn_fdot2(lf, at2[z], sc, false);
    }
    sc += __shfl_xor(sc, 1);
    sc += __shfl_xor(sc, 2);
    const float p = ok ? __builtin_exp2f(sc) : 0.f;
    S += p;
    const _Float16 ph = (_Float16)p;
    const h16x2 p2 = {ph, ph};
#pragma unroll
    for (int z = 0; z < 4; ++z) A2[z] = v2[z] * p2 + A2[z];
  }

  // combine the 4 edge subgroups (lanes l, l+16, l+32, l+48 share dims)
#pragma unroll
  for (int off = 16; off <= 32; off <<= 1) {
#pragma unroll
    for (int z = 0; z < 4; ++z) A2[z] = A2[z] + shfl_xor_h2(A2[z], off);
    S += __shfl_xor(S, off);
  }

  const float si = 1.0f / S;
  float o[8];
  float b8[8];
  *(float4*)&b8[0] = *(const float4*)&bias[q * 8];
  *(float4*)&b8[4] = *(const float4*)&bias[q * 8 + 4];
  float dot = 0.f;
#pragma unroll
  for (int z = 0; z < 4; ++z) {
    o[2 * z] = fmaf((float)A2[z][0], si, b8[2 * z]);
    o[2 * z + 1] = fmaf((float)A2[z][1], si, b8[2 * z + 1]);
    dot = fmaf(o[2 * z], o[2 * z], dot);
    dot = fmaf(o[2 * z + 1], o[2 * z + 1], dot);
  }
  const float nrm = sqrtf(waveReduceSum(dot) * 0.25f);  // dims replicated 4x
  const float gg = hnorm[i] * scale[0] / fmaxf(nrm, 1e-12f);

  if (lane < 16) {
    float x8[8];
    *(float4*)&x8[0] = *(const float4*)&x[(size_t)i * D + q * 8];
    *(float4*)&x8[4] = *(const float4*)&x[(size_t)i * D + q * 8 + 4];
    float r8[8];
#pragma unroll
    for (int z = 0; z < 8; ++z) r8[z] = fmaf(o[z], gg, x8[z]);
    *(float4*)&out[(size_t)i * D + q * 8] = *(float4*)&r8[0];
    *(float4*)&out[(size_t)i * D + q * 8 + 4] = *(float4*)&r8[4];
  }
}

extern "C" void kernel_launch(void* const* d_in, const int* in_sizes, int n_in,
                              void* d_out, int out_size, void* d_ws, size_t ws_size,
                              hipStream_t stream) {
  const float* x = (const float*)d_in[0];
  const int* ei = (const int*)d_in[1];
  const float* gamma = (const float*)d_in[2];
  const float* beta = (const float*)d_in[3];
  const float* Wl = (const float*)d_in[4];
  const float* bL = (const float*)d_in[5];
  const float* Wr = (const float*)d_in[6];
  const float* bR = (const float*)d_in[7];
  const float* att = (const float*)d_in[8];
  const float* bias = (const float*)d_in[9];
  const float* scale = (const float*)d_in[10];
  float* out = (float*)d_out;

  // workspace layout (~49 MB, 16B-aligned segments)
  int2* bucketed = (int2*)d_ws;         // E2 pairs
  int* csr = (int*)(bucketed + E2);     // E2 + 32 (sentinel pad)
  int* rowptr = csr + E2 + 32;          // N+1 (padded to N+16)
  int* bcnt = rowptr + N_NODES + 16;    // 256
  int* cnt0 = bcnt + 256;               // 256
  float* hnorm = (float*)(cnt0 + 256);  // N
  __hip_bfloat16* hb = (__hip_bfloat16*)(hnorm + N_NODES);
  __hip_bfloat16* Wt = hb + (size_t)N_NODES * D;  // 256*128
  _Float16* xlh = (_Float16*)(Wt + 256 * D);
  _Float16* xrh = xlh + (size_t)N_NODES * D;

  hipMemsetAsync(bcnt, 0, 512 * sizeof(int), stream);
  k_count<<<NB_SC, 256, 0, stream>>>(ei, bcnt);
  k_pre2<<<NB_SC + NB_LN + NB_W, 256, 0, stream>>>(x, gamma, beta, Wl, Wr, ei, bcnt,
                                                   cnt0, bucketed, hb, hnorm, Wt);
  k_mid<<<NBUCK + NB_GEMM, 256, 0, stream>>>(bucketed, bcnt, rowptr, csr, hb, Wt,
                                             bL, bR, xlh, xrh);
  k_node<<<(N_NODES + 3) / 4, 256, 0, stream>>>(x, xlh, xrh, hnorm, rowptr, csr, att,
                                                bias, scale, out);
}